// Round 10
// baseline (468.071 us; speedup 1.0000x reference)
//
#include <hip/hip_runtime.h>
#include <math.h>

#define CLASSNUM 70722
#define BATCH 512
#define EMBD 512
#define M_C 0.4f
#define H_C 0.333f
#define S_C 64.0f
#define EPS_C 0.001f
#define PI_F 3.14159265358979f

typedef __bf16 bf16_t;
typedef __bf16 bf16x8 __attribute__((ext_vector_type(8)));
typedef float f32x4 __attribute__((ext_vector_type(4)));

__device__ __forceinline__ float clampf(float x, float lo, float hi) {
    return fminf(fmaxf(x, lo), hi);
}

// ---------------------------------------------------------------------------
// prep: block 0 computes margin_scaler msw[512]; blocks 1..128 convert the
// embeddings to bf16 in MFMA-fragment order (fragment F(kt,rg) = rows
// [rg*16,rg*16+16) x k [kt*32,kt*32+32), 1 KB contiguous, lane-ordered).
// ---------------------------------------------------------------------------
__global__ __launch_bounds__(256) void prep_kernel(
    const float* __restrict__ emb, const float* __restrict__ norms,
    const float* __restrict__ csn, bf16_t* __restrict__ Aws,
    float* __restrict__ msw)
{
    __shared__ float sred[256];
    const int tid = threadIdx.x;
    if (blockIdx.x == 0) {
        float s0, s1;
        {
            float sn = clampf(norms[tid], 0.001f, 100.0f);
            sn = sn / (csn[tid] + 0.001f);
            s0 = clampf(sn, 0.001f, 100.0f);
        }
        {
            float sn = clampf(norms[tid + 256], 0.001f, 100.0f);
            sn = sn / (csn[tid + 256] + 0.001f);
            s1 = clampf(sn, 0.001f, 100.0f);
        }
        sred[tid] = s0 + s1;
        __syncthreads();
        for (int off = 128; off > 0; off >>= 1) {
            if (tid < off) sred[tid] += sred[tid + off];
            __syncthreads();
        }
        const float mean = sred[0] * (1.0f / 512.0f);
        __syncthreads();
        const float d0 = s0 - mean, d1 = s1 - mean;
        sred[tid] = d0 * d0 + d1 * d1;
        __syncthreads();
        for (int off = 128; off > 0; off >>= 1) {
            if (tid < off) sred[tid] += sred[tid + off];
            __syncthreads();
        }
        const float stdv = sqrtf(sred[0] * (1.0f / 511.0f));  // ddof=1
        const float inv = 1.0f / (stdv + EPS_C);
        msw[tid]       = clampf(d0 * inv * H_C, -1.0f, 1.0f);
        msw[tid + 256] = clampf(d1 * inv * H_C, -1.0f, 1.0f);
    } else {
        const int G = (blockIdx.x - 1) * 256 + tid;   // granule id, 0..32767
        const int kt = G >> 11;
        const int rem = G & 2047;
        const int rg = rem >> 6;
        const int lane = rem & 63;
        const int row = rg * 16 + (lane & 15);
        const int k0 = kt * 32 + (lane >> 4) * 8;
        const float* src = emb + row * EMBD + k0;
        const float4 v0 = *(const float4*)src;
        const float4 v1 = *(const float4*)(src + 4);
        bf16x8 bw;
        bw[0] = (bf16_t)v0.x; bw[1] = (bf16_t)v0.y;
        bw[2] = (bf16_t)v0.z; bw[3] = (bf16_t)v0.w;
        bw[4] = (bf16_t)v1.x; bw[5] = (bf16_t)v1.y;
        bw[6] = (bf16_t)v1.z; bw[7] = (bf16_t)v1.w;
        *(bf16x8*)(Aws + (size_t)G * 8) = bw;         // coalesced 16 B store
    }
}

// ---------------------------------------------------------------------------
// lab: one 256-thread block per batch row.  Exact fp32 dot(emb[b],
// K[:,label[b]]) + column norm + full margin formula -> labout[b].
// ---------------------------------------------------------------------------
__global__ __launch_bounds__(256) void lab_kernel(
    const float* __restrict__ emb, const int* __restrict__ label,
    const float* __restrict__ kmat, const float* __restrict__ msw,
    float* __restrict__ labout)
{
    __shared__ float red[256];
    const int b = blockIdx.x;
    const int tid = threadIdx.x;
    const int lab = label[b];
    const float* col = kmat + lab;
    const float* e = emb + b * EMBD;
    float dot = 0.0f, ss = 0.0f;
#pragma unroll
    for (int k = tid; k < EMBD; k += 256) {
        const float kv = col[(size_t)k * CLASSNUM];
        dot = fmaf(e[k], kv, dot);
        ss  = fmaf(kv, kv, ss);
    }
    red[tid] = dot;
    __syncthreads();
    for (int off = 128; off > 0; off >>= 1) {
        if (tid < off) red[tid] += red[tid + off];
        __syncthreads();
    }
    const float dotT = red[0];
    __syncthreads();
    red[tid] = ss;
    __syncthreads();
    for (int off = 128; off > 0; off >>= 1) {
        if (tid < off) red[tid] += red[tid + off];
        __syncthreads();
    }
    if (tid == 0) {
        float c = dotT / sqrtf(red[0]);
        c = clampf(c, -1.0f + EPS_C, 1.0f - EPS_C);
        const float msv = msw[b];
        float th = acosf(c) - M_C * msv;
        th = clampf(th, EPS_C, PI_F - EPS_C);
        labout[b] = (cosf(th) - (M_C + M_C * msv)) * S_C;
    }
}

// ---------------------------------------------------------------------------
// gemm v8 = v3 (117 us best) with BK=64: 8 K-steps instead of 16 -> HALF the
// barriers, CVT vmcnt-drains, and lockstep convergence events, at identical
// traffic.  NO setprio (m190: negative on barrier-synced GEMM; v3 -- the
// fastest variant -- never had it).
// Queue discipline per step s (A oldest, B youngest):
//   MFMA(af = A(2s), kk=0)            <- af loaded end of prev step, oldest
//   LOADA(2s+1) -> af in place (WAR)
//   MFMA(af = A(2s+1), kk=1)          <- forces B(s+1): already 1 step old
//   CVT B(s+1) regs -> Blds[buf^1]    <- its loads already retired: free
//   LOADA(2s+2) -> af                 <- next step's kk=0 operand
//   LOADB(s+2)                        <- youngest; ~2 steps of lead
//   lgkmcnt(0); s_barrier             <- VMEM loads cross the barrier
// Blds stride 72 bf16 (144 B): both the b128 staging writes and the b128
// frag reads spread over all 8 bank-quads (9 mod 8 = 1) -- balanced.
// 64 acc + ~60 VGPR stays inside the 128-reg / 4-waves-per-SIMD budget.
// ---------------------------------------------------------------------------

#define LOADB8(t, dst) do {                                             \
    const size_t ko_ = (size_t)((t) * 64) * CLASSNUM;                   \
    _Pragma("unroll")                                                   \
    for (int j_ = 0; j_ < 8; ++j_)                                      \
        dst[j_] = bp[ko_ + (size_t)j_ * CLASSNUM];                      \
} while (0)

#define LOADA4(t2, af) do {                                             \
    const bf16x8* ap_ = (const bf16x8*)Aws                              \
        + (((t2) * 32 + wave * 4) * 64 + lane);                         \
    _Pragma("unroll")                                                   \
    for (int mi_ = 0; mi_ < 4; ++mi_) af[mi_] = ap_[mi_ * 64];          \
} while (0)

#define CVTW8(src, buf) do {                                            \
    bf16x8 w_;                                                          \
    _Pragma("unroll")                                                   \
    for (int j_ = 0; j_ < 8; ++j_) {                                    \
        const float v_ = src[j_];                                       \
        ssq = fmaf(v_, v_, ssq);                                        \
        w_[j_] = (bf16_t)v_;                                            \
    }                                                                   \
    *(bf16x8*)&Blds[buf][c * 72 + kg * 8] = w_;                         \
} while (0)

#define MFMA16K(af, buf, kk) do {                                       \
    bf16x8 bfr_[4];                                                     \
    _Pragma("unroll")                                                   \
    for (int ni_ = 0; ni_ < 4; ++ni_)                                   \
        bfr_[ni_] = *(const bf16x8*)                                    \
            &Blds[buf][(ni_ * 16 + r16) * 72 + (kk) * 32 + quad * 8];   \
    _Pragma("unroll")                                                   \
    for (int mi_ = 0; mi_ < 4; ++mi_)                                   \
        _Pragma("unroll")                                               \
        for (int ni_ = 0; ni_ < 4; ++ni_)                               \
            acc[mi_][ni_] = __builtin_amdgcn_mfma_f32_16x16x32_bf16(    \
                af[mi_], bfr_[ni_], acc[mi_][ni_], 0, 0, 0);            \
} while (0)

#define BARRIER() do {                                                  \
    asm volatile("s_waitcnt lgkmcnt(0)" ::: "memory");                  \
    __builtin_amdgcn_s_barrier();                                       \
} while (0)

__global__ __launch_bounds__(512, 4) void gemm_kernel(
    const bf16_t* __restrict__ Aws, const float* __restrict__ Kmat,
    const int* __restrict__ label, const float* __restrict__ labout,
    float* __restrict__ out)
{
    __shared__ bf16_t Blds[2][64 * 72];     // 2 x 9 KB, stride-72 rows
    __shared__ float red[512];
    __shared__ float invn_s[64];
    __shared__ int   lab_s[BATCH];
    __shared__ float lo_s[BATCH];

    const int tid  = threadIdx.x;
    const int lane = tid & 63;
    const int wave = tid >> 6;              // 0..7
    const int r16  = lane & 15;
    const int quad = lane >> 4;

    // bijective XCD swizzle (nwg=1106 = 8*138+2)
    const int nwg = (CLASSNUM + 63) / 64;
    const int q_ = nwg >> 3, r_ = nwg & 7;
    const int xcd = blockIdx.x & 7, idx = blockIdx.x >> 3;
    const int nb = (xcd < r_) ? (xcd * (q_ + 1) + idx)
                              : (r_ * (q_ + 1) + (xcd - r_) * q_ + idx);
    const int n0 = nb * 64;

    lab_s[tid] = label[tid];
    lo_s[tid]  = labout[tid];

    // B cooperative-load ownership: col c (0..63), k-group kg (0..7) of 8 k.
    const int c  = tid & 63;
    const int kg = tid >> 6;
    int cg = n0 + c;
    if (cg >= CLASSNUM) cg = CLASSNUM - 1;   // clamp; stores are guarded
    const float* bp = Kmat + (size_t)(kg * 8) * CLASSNUM + cg;

    f32x4 acc[4][4];
    const f32x4 zero = {0.0f, 0.0f, 0.0f, 0.0f};
#pragma unroll
    for (int i = 0; i < 4; ++i)
#pragma unroll
        for (int j = 0; j < 4; ++j) acc[i][j] = zero;
    float ssq = 0.0f;

    float bv0[8], bv1[8];   // B(t) lives in bv[t&1]
    bf16x8 af[4];

    // ---- prologue: A(0) oldest, then B(0), B(1); stage B(0)->Blds[0] ----
    LOADA4(0, af);
    LOADB8(0, bv0);
    LOADB8(1, bv1);
    CVTW8(bv0, 0);
    BARRIER();

    // ---- K loop: 8 steps of 64 k, hand-unrolled x2 (static indices) ----
#pragma unroll 1
    for (int p = 0; p < 4; ++p) {
        {   // step s = 2p (even, Blds[0]); stage B(2p+1) -> Blds[1]
            MFMA16K(af, 0, 0);              // A slab 4p
            LOADA4(4 * p + 1, af);
            MFMA16K(af, 0, 1);              // A slab 4p+1
            CVTW8(bv1, 1);
            LOADA4(4 * p + 2, af);          // next step kk=0
            if (p < 3) LOADB8(2 * p + 2, bv0);
            BARRIER();
        }
        {   // step s = 2p+1 (odd, Blds[1]); stage B(2p+2) -> Blds[0]
            MFMA16K(af, 1, 0);              // A slab 4p+2
            LOADA4(4 * p + 3, af);
            MFMA16K(af, 1, 1);              // A slab 4p+3
            if (p < 3) {
                CVTW8(bv0, 0);
                LOADA4(4 * p + 4, af);
                LOADB8(2 * p + 3, bv1);
            }
            BARRIER();
        }
    }

    // ---- column inverse norms: 8 k-partials per column (kg groups) ----
    red[tid] = ssq;
    __syncthreads();
    if (tid < 64) {
        float s = 0.0f;
#pragma unroll
        for (int g = 0; g < 8; ++g) s += red[tid + g * 64];
        invn_s[tid] = (s > 0.0f) ? (1.0f / sqrtf(s)) : 0.0f;
    }
    __syncthreads();

    // ---- epilogue: out = S * clip(cosine); label entries substituted.
    // ni innermost: 4 consecutive stores cover 256 B contiguous per row. ----
#pragma unroll
    for (int mi = 0; mi < 4; ++mi) {
#pragma unroll
        for (int rr = 0; rr < 4; ++rr) {
            const int row = wave * 64 + mi * 16 + quad * 4 + rr;
            const int labc = lab_s[row];
            const float lov = lo_s[row];
            float* orow = out + (size_t)row * CLASSNUM;
#pragma unroll
            for (int ni = 0; ni < 4; ++ni) {
                const int col_loc = ni * 16 + r16;
                const int col = n0 + col_loc;
                if (col < CLASSNUM) {
                    const float cc = clampf(acc[mi][ni][rr] * invn_s[col_loc],
                                            -1.0f + EPS_C, 1.0f - EPS_C);
                    float v = cc * S_C;
                    if (labc == col) v = lov;
                    orow[col] = v;
                }
            }
        }
    }
}

// ---------------------------------------------------------------------------
// scatter: overwrite the 512 (row, label) entries with the exact fp32 values.
// (Redundant with the in-gemm substitution -- writes identical values; ~2 us.)
// ---------------------------------------------------------------------------
__global__ __launch_bounds__(512) void scatter_kernel(
    const int* __restrict__ label, const float* __restrict__ labout,
    float* __restrict__ out)
{
    const int t = threadIdx.x;
    out[(size_t)t * CLASSNUM + label[t]] = labout[t];
}

extern "C" void kernel_launch(void* const* d_in, const int* in_sizes, int n_in,
                              void* d_out, int out_size, void* d_ws, size_t ws_size,
                              hipStream_t stream)
{
    const float* emb   = (const float*)d_in[0];
    const float* norms = (const float*)d_in[1];
    const int*   label = (const int*)d_in[2];
    const float* csn   = (const float*)d_in[3];
    const float* kmat  = (const float*)d_in[4];
    float* out = (float*)d_out;

    // workspace: [A bf16 fragment-tiled 512x512 | msw 512 | labout 512]
    const size_t A_BYTES = (size_t)BATCH * EMBD * sizeof(bf16_t);  // 524288
    if (ws_size < A_BYTES + 4096) return;
    bf16_t* Aws   = (bf16_t*)d_ws;
    float* msw    = (float*)((char*)d_ws + A_BYTES);
    float* labout = (float*)((char*)d_ws + A_BYTES + 2048);

    prep_kernel<<<129, 256, 0, stream>>>(emb, norms, csn, Aws, msw);
    lab_kernel<<<BATCH, 256, 0, stream>>>(emb, label, kmat, msw, labout);
    const int nblk = (CLASSNUM + 63) / 64;   // 1106
    gemm_kernel<<<nblk, 512, 0, stream>>>(Aws, kmat, label, labout, out);
    scatter_kernel<<<1, 512, 0, stream>>>(label, labout, out);
}